// Round 1
// 100.188 us; speedup vs baseline: 1.0059x; 1.0059x over previous
//
#include <hip/hip_runtime.h>
#include <hip/hip_fp16.h>
#include <math.h>

#define DD 384
#define HD 1024
#define CD 256
#define NS 765        // 2*DD-1 shifts
#define NITER 4
#define NROWS 256     // B*T
#define TEMPER_F 10.0f
#define EPSF 1e-6f
#define CUTF 1e-10f

typedef unsigned long long u64;
typedef unsigned int u32;
typedef _Float16 hh2 __attribute__((ext_vector_type(2)));

// monotone float->uint (ascending)
__device__ __forceinline__ u32 flipf(float f) {
    u32 u = __float_as_uint(f);
    return u ^ ((u32)((int)u >> 31) | 0x80000000u);
}
// fp32 pair -> packed f16 (RTN-ish pack)
__device__ __forceinline__ u32 packh2(float a, float b) {
    __half2 p = __floats2half2_rn(a, b);
    return __builtin_bit_cast(u32, p);
}
// fp32 += dot2(f16x2, f16x2)
__device__ __forceinline__ float dot2(u32 a, u32 b, float c) {
#if __has_builtin(__builtin_amdgcn_fdot2)
    return __builtin_amdgcn_fdot2(__builtin_bit_cast(hh2, a),
                                  __builtin_bit_cast(hh2, b), c, false);
#else
    __half2 ah = __builtin_bit_cast(__half2, a);
    __half2 bh = __builtin_bit_cast(__half2, b);
    return fmaf(__half2float(ah.y), __half2float(bh.y),
           fmaf(__half2float(ah.x), __half2float(bh.x), c));
#endif
}

// ---- 0) convert weights: Wenc -> f16 K-paired [192][1024] u32 (as uint4 quads);
//         Wdec -> f16 col-paired [1024][192] u32 ----
// Vectorized: Wenc path reads 2 coalesced float4 rows, writes 1 uint4.
__global__ __launch_bounds__(256) void convert_kernel(
    const float* __restrict__ We, const float* __restrict__ Wd,
    uint4* __restrict__ wencp4, uint2* __restrict__ wd16)
{
    const int t = blockIdx.x * 256 + threadIdx.x;      // 65536 threads
    if (t < 192 * 256) {                               // row-pair j2, col-quad c4
        const int j2 = t >> 8, c4 = t & 255;
        float4 a = *(const float4*)&We[(2 * j2)     * HD + 4 * c4];
        float4 b = *(const float4*)&We[(2 * j2 + 1) * HD + 4 * c4];
        wencp4[j2 * 256 + c4] = make_uint4(packh2(a.x, b.x), packh2(a.y, b.y),
                                           packh2(a.z, b.z), packh2(a.w, b.w));
    }
    for (int i = t; i < (HD * DD) / 4; i += 65536) {
        float4 v = ((const float4*)Wd)[i];
        wd16[i] = make_uint2(packh2(v.x, v.y), packh2(v.z, v.w));
    }
}

// One 1024-thread block per row: prep -> fdot2 encoder -> HISTOGRAM SELECT
// (exact rank-255/511/767 boundary keys; replaces full bitonic sort) ->
// ballot-compaction partition -> 2-pass balanced decode (f16 pairwise fdot2).
// NOTE: loss/ycnt leave the kernel as plain per-row stores; finalize is a
// separate dispatch. Agent-scope fences/atomics in-kernel regressed 3x (R6,R15).
__global__ __launch_bounds__(1024) void fused_kernel(
    const float* __restrict__ x, const float* __restrict__ y,
    const u32* __restrict__ wencp, const float* __restrict__ benc,
    const u32* __restrict__ wdec16, const float* __restrict__ bdec,
    float* __restrict__ out_xdis, float* __restrict__ lossp,
    int* __restrict__ ycnt)
{
    const int row  = blockIdx.x;
    const int tid  = threadIdx.x;
    const int lane = tid & 63;
    const int wid  = tid >> 6;       // 0..15

    __shared__ __align__(16) float xpad[1152];
    __shared__ __align__(16) float yr[DD];
    __shared__ float xa[DD];
    __shared__ __align__(16) float xe_s[DD];
    __shared__ u32   xep[192];                    // xe packed f16 pairs
    __shared__ __align__(16) float part[4][HD];   // enc partials; reused as hist[4096]
    __shared__ __align__(16) uint2 dec2[HD];      // {bits(v), idx*192}
    __shared__ __align__(16) float4 dpart[8][96]; // decode half-partials
    __shared__ float wred[16];
    __shared__ int   wredi[16];
    __shared__ float wredn[16];
    __shared__ int   wbase16[16];
    __shared__ float s_sc[4];
    __shared__ int   s_theta;
    __shared__ u32   s_b[3];
    __shared__ int   sbinB[3], srankB[3], s_cc[3];
    __shared__ u32   cand[3][64];
    __shared__ int   wcls[128];                   // per (class, wave) counts
    __shared__ int   sbase[128];                  // exclusive scan
    __shared__ int   cnt8[8];
    __shared__ float loss4[NITER];

    const float* xrow = x + row * DD;
    const float* yrow = y + row * DD;

    for (int i = tid; i < 1152; i += 1024)
        xpad[i] = (i >= DD - 1 && i < 2 * DD - 1) ? xrow[i - (DD - 1)] : 0.f;
    if (tid < DD) yr[tid] = yrow[tid];
    __syncthreads();

    // ---- qn = ||y|| (+ y-count) ----
    if (tid < DD) {
        float p = yr[tid] * yr[tid];
        int   c = (yr[tid] != 0.f) ? 1 : 0;
        for (int o = 32; o; o >>= 1) {
            p += __shfl_xor(p, o, 64);
            c += __shfl_xor(c, o, 64);
        }
        if (lane == 0) { wred[wid] = p; wredi[wid] = c; }
    }
    __syncthreads();
    if (tid == 0) {
        float s = 0.f; int c = 0;
        for (int w = 0; w < 6; ++w) { s += wred[w]; c += wredi[w]; }
        s_sc[0] = sqrtf(s);
        ycnt[row] = c;
    }
    __syncthreads();
    const float qn = s_sc[0];

    // ---- sim argmax: threads 0..191, 4 consecutive shifts, sliding window ----
    float bv = -INFINITY; int bs = 0x7fffffff; float bn = 0.f;
    if (tid < 192) {
        const float4* xp4 = (const float4*)xpad;
        const float4* yp4 = (const float4*)yr;
        float4 A = xp4[tid];
        const float f0 = A.x * A.x, f1 = A.y * A.y, f2 = A.z * A.z;
        float d0 = 0.f, d1 = 0.f, d2 = 0.f, d3 = 0.f, n0 = 0.f;
#pragma unroll 4
        for (int jc = 0; jc < 96; ++jc) {
            float4 B = xp4[tid + jc + 1];
            float4 Y = yp4[jc];
            d0 += A.x * Y.x; d0 += A.y * Y.y; d0 += A.z * Y.z; d0 += A.w * Y.w;
            d1 += A.y * Y.x; d1 += A.z * Y.y; d1 += A.w * Y.z; d1 += B.x * Y.w;
            d2 += A.z * Y.x; d2 += A.w * Y.y; d2 += B.x * Y.z; d2 += B.y * Y.w;
            d3 += A.w * Y.x; d3 += B.x * Y.y; d3 += B.y * Y.z; d3 += B.z * Y.w;
            n0 += A.x * A.x; n0 += A.y * A.y; n0 += A.z * A.z; n0 += A.w * A.w;
            A = B;
        }
        const float n1 = n0 - f0 + A.x * A.x;
        const float n2 = n1 - f1 + A.y * A.y;
        const float n3 = n2 - f2 + A.z * A.z;
        const int s0 = 4 * tid;
        float sim0 = d0 / (qn * sqrtf(n0) + EPSF);
        float sim1 = d1 / (qn * sqrtf(n1) + EPSF);
        float sim2 = d2 / (qn * sqrtf(n2) + EPSF);
        float sim3 = d3 / (qn * sqrtf(n3) + EPSF);
        bv = sim0; bs = s0; bn = n0;
        if (s0 + 1 < NS && sim1 > bv) { bv = sim1; bs = s0 + 1; bn = n1; }
        if (s0 + 2 < NS && sim2 > bv) { bv = sim2; bs = s0 + 2; bn = n2; }
        if (s0 + 3 < NS && sim3 > bv) { bv = sim3; bs = s0 + 3; bn = n3; }
    }
    for (int o = 32; o; o >>= 1) {
        float v2 = __shfl_xor(bv, o, 64);
        int   i2 = __shfl_xor(bs, o, 64);
        float n2 = __shfl_xor(bn, o, 64);
        if (v2 > bv || (v2 == bv && i2 < bs)) { bv = v2; bs = i2; bn = n2; }
    }
    if (lane == 0) { wred[wid] = bv; wredi[wid] = bs; wredn[wid] = bn; }
    __syncthreads();
    if (tid == 0) {
        float v = wred[0]; int b = wredi[0]; float nn = wredn[0];
        for (int w = 1; w < 16; ++w)
            if (wred[w] > v || (wred[w] == v && wredi[w] < b)) {
                v = wred[w]; b = wredi[w]; nn = wredn[w];
            }
        s_theta = b;
        s_sc[1] = sqrtf(nn) * qn + EPSF;      // dn from carried nrm(theta)
    }
    __syncthreads();
    const int theta = s_theta;
    const float dn = s_sc[1];

    // ---- softmax without max-pass (|z| <= 0.1 by Cauchy-Schwarz) ----
    float xo = 0.f, ez = 0.f;
    if (tid < DD) {
        xo = xpad[theta + tid];
        ez = expf((xo * yr[tid] / dn) / TEMPER_F);
        float p = ez;
        for (int o = 32; o; o >>= 1) p += __shfl_xor(p, o, 64);
        if (lane == 0) wred[wid] = p;
    }
    __syncthreads();
    if (tid == 0) {
        float s = 0.f;
        for (int w = 0; w < 6; ++w) s += wred[w];
        s_sc[3] = s;
    }
    __syncthreads();
    if (tid < DD) xa[tid] = xo * (ez / s_sc[3]);
    __syncthreads();
    if (tid < DD) {
        int sj = tid - (theta - (DD - 1));
        xe_s[tid] = (sj >= 0 && sj < DD) ? xa[sj] : 0.f;
    }
    __syncthreads();
    if (tid < 192) xep[tid] = packh2(xe_s[2 * tid], xe_s[2 * tid + 1]);
    __syncthreads();

    // ---- encoder: K-split 4x, f16 pairs, fdot2 ----
    {
        const int ks = tid >> 8;              // 0..3 (wave-uniform)
        const int c4 = tid & 255;
        const uint4* wq = (const uint4*)wencp + (size_t)(ks * 48) * 256 + c4;
        const u32* xb = xep + ks * 48;
        float4 acc = make_float4(0.f, 0.f, 0.f, 0.f);
#pragma unroll 8
        for (int j2 = 0; j2 < 48; ++j2) {
            u32 xv = xb[j2];                  // broadcast
            uint4 w = wq[(size_t)j2 * 256];
            acc.x = dot2(xv, w.x, acc.x);
            acc.y = dot2(xv, w.y, acc.y);
            acc.z = dot2(xv, w.z, acc.z);
            acc.w = dot2(xv, w.w, acc.w);
        }
        *(float4*)&part[ks][4 * c4] = acc;
    }
    if (tid < 8) cnt8[tid] = 0;
    if (tid < NITER) loss4[tid] = 0.f;
    __syncthreads();

    const float oh = part[0][tid] + part[1][tid] + part[2][tid] + part[3][tid]
                   + benc[tid];
    const u32 okey = ~flipf(oh);              // ascending key == descending h
    __syncthreads();                          // all reads of part done

    // ---- histogram select: exact boundary keys at ranks 255/511/767 ----
    u32* hist = (u32*)part;                   // 4096 bins aliased on dead partials
    {
        hist[tid] = 0; hist[tid + 1024] = 0;
        hist[tid + 2048] = 0; hist[tid + 3072] = 0;
        if (tid < 192) cand[tid >> 6][tid & 63] = 0xFFFFFFFFu;
        if (tid < 3) s_cc[tid] = 0;
        __syncthreads();
        atomicAdd(&hist[okey >> 20], 1u);
        __syncthreads();
        // hierarchical exclusive scan: 4 bins/thread
        const int t4 = tid << 2;
        const u32 l0 = hist[t4], l1 = hist[t4 + 1], l2 = hist[t4 + 2], l3 = hist[t4 + 3];
        const int s = (int)(l0 + l1 + l2 + l3);
        int inc = s;
        for (int o = 1; o < 64; o <<= 1) {
            int u = __shfl_up(inc, o, 64);
            if (lane >= o) inc += u;
        }
        if (lane == 63) wredi[wid] = inc;
        __syncthreads();
        if (tid == 0) {
            int acc = 0;
            for (int w = 0; w < 16; ++w) { wbase16[w] = acc; acc += wredi[w]; }
        }
        __syncthreads();
        const int c0 = wbase16[wid] + inc - s;            // cum before bin t4
        const int c1 = c0 + (int)l0, c2 = c1 + (int)l1, c3 = c2 + (int)l2;
        const int c4e = c3 + (int)l3;
#pragma unroll
        for (int i = 0; i < 3; ++i) {
            const int R = 255 + (i << 8);
            if (R >= c0 && R < c1)      { sbinB[i] = t4;     srankB[i] = R - c0; }
            else if (R >= c1 && R < c2) { sbinB[i] = t4 + 1; srankB[i] = R - c1; }
            else if (R >= c2 && R < c3) { sbinB[i] = t4 + 2; srankB[i] = R - c2; }
            else if (R >= c3 && R < c4e){ sbinB[i] = t4 + 3; srankB[i] = R - c3; }
        }
        __syncthreads();
        // extract candidates of the 3 boundary bins
        const int myb = (int)(okey >> 20);
#pragma unroll
        for (int i = 0; i < 3; ++i) {
            if (myb == sbinB[i]) {
                int slot = atomicAdd(&s_cc[i], 1);
                if (slot < 64) cand[i][slot] = okey;
            }
        }
        __syncthreads();
        // 3 waves each sort 64 candidates in-register; pick intra-bin rank
        if (wid < 3) {
            u32 v = cand[wid][lane];
            for (int k2 = 2; k2 <= 64; k2 <<= 1) {
                for (int j = k2 >> 1; j > 0; j >>= 1) {
                    u32 p = __shfl_xor(v, j, 64);
                    const bool takeMin = ((lane & j) == 0) == ((lane & k2) == 0);
                    v = takeMin ? (v < p ? v : p) : (v > p ? v : p);
                }
            }
            if (lane == srankB[wid]) s_b[wid] = v;
        }
        __syncthreads();
    }
    const u32 b1 = s_b[0], b2 = s_b[1], b3 = s_b[2];

    // ---- partition: class = 2*quartile + (below-cutoff); ballot compaction ----
    {
        const int myk = (okey <= b1) ? 0 : (okey <= b2) ? 1 : (okey <= b3) ? 2 : 3;
        const int cls = 2 * myk + ((oh > CUTF) ? 0 : 1);
        int myprefix = 0;
        const u64 ltmask = (1ull << lane) - 1;
#pragma unroll
        for (int c = 0; c < 8; ++c) {
            u64 m = __ballot(cls == c);
            if (cls == c) myprefix = __popcll(m & ltmask);
            if (lane == 0) {
                wcls[c * 16 + wid] = (int)__popcll(m);
                atomicAdd(&cnt8[c], (int)__popcll(m));
            }
        }
        __syncthreads();
        if (tid < 128) {
            int v = wcls[tid];
            int inc = v;
            for (int o = 1; o < 64; o <<= 1) {
                int t2 = __shfl_up(inc, o, 64);
                if (lane >= o) inc += t2;
            }
            sbase[tid] = inc - v;             // wave-local exclusive
        }
        __syncthreads();
        if (tid >= 64 && tid < 128) sbase[tid] += sbase[63] + wcls[63];
        __syncthreads();
        const int slot = sbase[cls * 16 + wid] + myprefix;
        dec2[slot] = make_uint2(__float_as_uint(oh), (u32)tid * 192u);
    }
    __syncthreads();

    // ---- decode pass 1: 8 groups of 128 thr = (k, rank-half); 4 cols/thread ----
    // f16 weights, entries consumed in PAIRS via v_dot2_f32_f16:
    //   vp = (v0,v1) packed f16; col pair = merged lo/hi halves of w0,w1.
    {
        const int g8 = tid >> 7;              // 0..7
        const int k  = g8 >> 1;               // wave-uniform
        const int hf = g8 & 1;
        const int gg = tid & 127;
        const bool active = (gg < 96);        // 96 col-quads = 384 cols
        int n = 0;
        if (active) n = (k == 0) ? CD : cnt8[2 * k];
        int r  = hf * 128;
        int r1 = n < r + 128 ? n : r + 128;
        if (r1 < r) r1 = r;
        float4 acc = make_float4(0.f, 0.f, 0.f, 0.f);
        const u32* wd = wdec16 + 2 * gg;      // col-pairs 2gg, 2gg+1
        const int base = k * CD;
        for (; r + 8 <= r1; r += 8) {
#pragma unroll
            for (int q = 0; q < 8; q += 2) {
                uint4 dv = *(const uint4*)&dec2[base + r + q];
                u32 vp = packh2(__uint_as_float(dv.x), __uint_as_float(dv.z));
                uint2 w0 = *(const uint2*)(wd + dv.y);
                uint2 w1 = *(const uint2*)(wd + dv.w);
                u32 p0 = (w0.x & 0xffffu) | (w1.x << 16);      // col 4gg
                u32 p1 = (w0.x >> 16) | (w1.x & 0xffff0000u);  // col 4gg+1
                u32 p2 = (w0.y & 0xffffu) | (w1.y << 16);      // col 4gg+2
                u32 p3 = (w0.y >> 16) | (w1.y & 0xffff0000u);  // col 4gg+3
                acc.x = dot2(vp, p0, acc.x);
                acc.y = dot2(vp, p1, acc.y);
                acc.z = dot2(vp, p2, acc.z);
                acc.w = dot2(vp, p3, acc.w);
            }
        }
        // pair tail within remaining [r, r1)
        for (; r + 2 <= r1; r += 2) {
            uint4 dv = *(const uint4*)&dec2[base + r];
            u32 vp = packh2(__uint_as_float(dv.x), __uint_as_float(dv.z));
            uint2 w0 = *(const uint2*)(wd + dv.y);
            uint2 w1 = *(const uint2*)(wd + dv.w);
            u32 p0 = (w0.x & 0xffffu) | (w1.x << 16);
            u32 p1 = (w0.x >> 16) | (w1.x & 0xffff0000u);
            u32 p2 = (w0.y & 0xffffu) | (w1.y << 16);
            u32 p3 = (w0.y >> 16) | (w1.y & 0xffff0000u);
            acc.x = dot2(vp, p0, acc.x);
            acc.y = dot2(vp, p1, acc.y);
            acc.z = dot2(vp, p2, acc.z);
            acc.w = dot2(vp, p3, acc.w);
        }
        if (r < r1) {                          // odd single entry
            uint2 dv = dec2[base + r];
            float v0 = __uint_as_float(dv.x);
            uint2 w0 = *(const uint2*)(wd + dv.y);
            u32 vlo = packh2(v0, 0.f), vhi = packh2(0.f, v0);
            acc.x = dot2(vlo, w0.x, acc.x);
            acc.y = dot2(vhi, w0.x, acc.y);
            acc.z = dot2(vlo, w0.y, acc.z);
            acc.w = dot2(vhi, w0.y, acc.w);
        }
        if (active) dpart[g8][gg] = acc;
    }
    __syncthreads();

    // ---- decode pass 2: combine halves, store, loss ----
    {
        float l = 0.f;
        if (tid < 512) {
            const int k2 = tid >> 7;          // wave-uniform
            const int q  = tid & 127;
            if (q < 96) {
                float4 a = dpart[2 * k2][q];
                float4 b = dpart[2 * k2 + 1][q];
                float4 bb = *(const float4*)&bdec[4 * q];
                float4 o4;
                o4.x = a.x + b.x + bb.x;
                o4.y = a.y + b.y + bb.y;
                o4.z = a.z + b.z + bb.z;
                o4.w = a.w + b.w + bb.w;
                *(float4*)&out_xdis[((size_t)k2 * NROWS + row) * DD + 4 * q] = o4;
                float4 xv = *(const float4*)&xrow[4 * q];
                float4 yv = *(const float4*)&yr[4 * q];
                float ee;
                ee = o4.x - xv.x; if (yv.x != 0.f) l += ee * ee;
                ee = o4.y - xv.y; if (yv.y != 0.f) l += ee * ee;
                ee = o4.z - xv.z; if (yv.z != 0.f) l += ee * ee;
                ee = o4.w - xv.w; if (yv.w != 0.f) l += ee * ee;
            }
        }
        for (int o = 32; o; o >>= 1) l += __shfl_xor(l, o, 64);
        if (tid < 512 && lane == 0) atomicAdd(&loss4[tid >> 7], l);
    }
    __syncthreads();
    if (tid < NITER) lossp[row * NITER + tid] = loss4[tid];
}

// ---- finalize: losses[k] = sum_rows lossp / sum_rows ycnt ----
__global__ __launch_bounds__(256) void finalize2(
    const float* __restrict__ lossp, const int* __restrict__ ycnt,
    float* __restrict__ losses)
{
    const int tid = threadIdx.x, lane = tid & 63, w = tid >> 6;
    __shared__ int ctot[4];
    int c = ycnt[tid];
    for (int o = 32; o; o >>= 1) c += __shfl_xor(c, o, 64);
    if (lane == 0) ctot[w] = c;
    __syncthreads();
    const int total = ctot[0] + ctot[1] + ctot[2] + ctot[3];
    float s = lossp[lane * NITER + w] + lossp[(lane + 64) * NITER + w]
            + lossp[(lane + 128) * NITER + w] + lossp[(lane + 192) * NITER + w];
    for (int o = 32; o; o >>= 1) s += __shfl_xor(s, o, 64);
    if (lane == 0) losses[w] = s / (float)total;
}

extern "C" void kernel_launch(void* const* d_in, const int* in_sizes, int n_in,
                              void* d_out, int out_size, void* d_ws, size_t ws_size,
                              hipStream_t stream) {
    const float* x    = (const float*)d_in[0];
    const float* y    = (const float*)d_in[1];
    const float* Wenc = (const float*)d_in[2];
    const float* benc = (const float*)d_in[3];
    const float* Wdec = (const float*)d_in[4];
    const float* bdec = (const float*)d_in[5];

    float* out  = (float*)d_out;
    float* loss = out + (out_size - NITER);

    // workspace (all regions fully written before read each launch; 16B-aligned)
    float* lossp  = (float*)d_ws;                          // 1024 floats
    int*   ycnt   = (int*)(lossp + NROWS * NITER);         // 256 ints
    u32*   wencp  = (u32*)(ycnt + NROWS);                  // 196608 u32 (f16 K-pairs)
    u32*   wdec16 = wencp + 192 * HD;                      // 196608 u32 (f16 col-pairs)

    convert_kernel<<<256, 256, 0, stream>>>(Wenc, Wdec, (uint4*)wencp,
                                            (uint2*)wdec16);
    fused_kernel<<<NROWS, 1024, 0, stream>>>(x, y, wencp, benc, wdec16, bdec,
                                             out, lossp, ycnt);
    finalize2<<<1, 256, 0, stream>>>(lossp, ycnt, loss);
}

// Round 2
// 99.238 us; speedup vs baseline: 1.0155x; 1.0096x over previous
//
#include <hip/hip_runtime.h>
#include <hip/hip_fp16.h>
#include <math.h>

#define DD 384
#define HD 1024
#define CD 256
#define NS 765        // 2*DD-1 shifts
#define NITER 4
#define NROWS 256     // B*T
#define TEMPER_F 10.0f
#define EPSF 1e-6f
#define CUTF 1e-10f

typedef unsigned long long u64;
typedef unsigned int u32;
typedef _Float16 hh2 __attribute__((ext_vector_type(2)));

// monotone float->uint (ascending)
__device__ __forceinline__ u32 flipf(float f) {
    u32 u = __float_as_uint(f);
    return u ^ ((u32)((int)u >> 31) | 0x80000000u);
}
// fp32 pair -> packed f16
__device__ __forceinline__ u32 packh2(float a, float b) {
    __half2 p = __floats2half2_rn(a, b);
    return __builtin_bit_cast(u32, p);
}
// fp32 += dot2(f16x2, f16x2)
__device__ __forceinline__ float dot2(u32 a, u32 b, float c) {
#if __has_builtin(__builtin_amdgcn_fdot2)
    return __builtin_amdgcn_fdot2(__builtin_bit_cast(hh2, a),
                                  __builtin_bit_cast(hh2, b), c, false);
#else
    __half2 ah = __builtin_bit_cast(__half2, a);
    __half2 bh = __builtin_bit_cast(__half2, b);
    return fmaf(__half2float(ah.y), __half2float(bh.y),
           fmaf(__half2float(ah.x), __half2float(bh.x), c));
#endif
}

// ---- 0) convert weights: Wenc -> f16 K-paired [192][1024] u32 (as uint4 quads);
//         Wdec -> f16 col-paired [1024][192] u32 ----
__global__ __launch_bounds__(256) void convert_kernel(
    const float* __restrict__ We, const float* __restrict__ Wd,
    uint4* __restrict__ wencp4, uint2* __restrict__ wd16)
{
    const int t = blockIdx.x * 256 + threadIdx.x;      // 65536 threads
    if (t < 192 * 256) {                               // row-pair j2, col-quad c4
        const int j2 = t >> 8, c4 = t & 255;
        float4 a = *(const float4*)&We[(2 * j2)     * HD + 4 * c4];
        float4 b = *(const float4*)&We[(2 * j2 + 1) * HD + 4 * c4];
        wencp4[j2 * 256 + c4] = make_uint4(packh2(a.x, b.x), packh2(a.y, b.y),
                                           packh2(a.z, b.z), packh2(a.w, b.w));
    }
    for (int i = t; i < (HD * DD) / 4; i += 65536) {
        float4 v = ((const float4*)Wd)[i];
        wd16[i] = make_uint2(packh2(v.x, v.y), packh2(v.z, v.w));
    }
}

// One 1024-thread block per row. Front half restructured for wave-level task
// parallelism: 12 waves compute 4-way-split sim partials while waves 12-15
// do the y-norm reduction AND zero hist2/cand/counters concurrently.
// Softmax is barrier-minimized via deterministic expf recompute (bit-identical
// oh/okey to the previous passing kernel). Select/partition/decode unchanged.
// NOTE: loss/ycnt leave the kernel as plain per-row stores; finalize is a
// separate dispatch. Agent-scope fences/atomics in-kernel regressed 3x (R6,R15).
__global__ __launch_bounds__(1024) void fused_kernel(
    const float* __restrict__ x, const float* __restrict__ y,
    const u32* __restrict__ wencp, const float* __restrict__ benc,
    const u32* __restrict__ wdec16, const float* __restrict__ bdec,
    float* __restrict__ out_xdis, float* __restrict__ lossp,
    int* __restrict__ ycnt)
{
    const int row  = blockIdx.x;
    const int tid  = threadIdx.x;
    const int lane = tid & 63;
    const int wid  = tid >> 6;       // 0..15

    __shared__ __align__(16) float xpad[1152];
    __shared__ __align__(16) float yr[DD];
    __shared__ u32   xep[192];                    // xe packed f16 pairs
    __shared__ __align__(16) float part[4][HD];   // enc partials
    __shared__ __align__(16) u32   hist2[4096];   // dedicated histogram
    __shared__ float spart[4 * 192 * 5];          // sim partials {d0..d3,n}
    __shared__ __align__(16) uint2 dec2[HD];      // {bits(v), idx*192}
    __shared__ __align__(16) float4 dpart[8][96]; // decode half-partials
    __shared__ float wred[16];
    __shared__ int   wredi[16];
    __shared__ float wredn[16];
    __shared__ int   wbase16[16];
    __shared__ float s_sc[4];
    __shared__ int   s_theta;
    __shared__ u32   s_b[3];
    __shared__ int   sbinB[3], srankB[3], s_cc[3];
    __shared__ u32   cand[3][64];
    __shared__ int   wcls[128];                   // per (class, wave) counts
    __shared__ int   sbase[128];                  // exclusive scan
    __shared__ int   cnt8[8];
    __shared__ float loss4[NITER];

    const float* xrow = x + row * DD;
    const float* yrow = y + row * DD;

    // ---- phase 1: prep ----
    for (int i = tid; i < 1152; i += 1024)
        xpad[i] = (i >= DD - 1 && i < 2 * DD - 1) ? xrow[i - (DD - 1)] : 0.f;
    if (tid < DD) yr[tid] = yrow[tid];
    __syncthreads();

    // ---- phase 2: sim partials (waves 0-11) || y-norm + zero/init (12-15) ----
    if (tid < 768) {
        const int qid = tid / 192, t = tid - qid * 192;  // qid wave-uniform
        const int jb = 24 * qid;
        const float4* xp4 = (const float4*)xpad;
        const float4* yp4 = (const float4*)yr;
        float4 A = xp4[t + jb];
        float d0 = 0.f, d1 = 0.f, d2 = 0.f, d3 = 0.f, n0 = 0.f;
#pragma unroll 8
        for (int jc = 0; jc < 24; ++jc) {
            float4 B = xp4[t + jb + jc + 1];
            float4 Y = yp4[jb + jc];
            d0 += A.x * Y.x; d0 += A.y * Y.y; d0 += A.z * Y.z; d0 += A.w * Y.w;
            d1 += A.y * Y.x; d1 += A.z * Y.y; d1 += A.w * Y.z; d1 += B.x * Y.w;
            d2 += A.z * Y.x; d2 += A.w * Y.y; d2 += B.x * Y.z; d2 += B.y * Y.w;
            d3 += A.w * Y.x; d3 += B.x * Y.y; d3 += B.y * Y.z; d3 += B.z * Y.w;
            n0 += A.x * A.x; n0 += A.y * A.y; n0 += A.z * A.z; n0 += A.w * A.w;
            A = B;
        }
        float* sp = &spart[(qid * 192 + t) * 5];
        sp[0] = d0; sp[1] = d1; sp[2] = d2; sp[3] = d3; sp[4] = n0;
    } else {
        const int i = tid - 768;          // 0..255 (waves 12-15)
        if (i < 192) {                    // waves 12-14: y^2 + count
            float y0 = yr[2 * i], y1 = yr[2 * i + 1];
            float p = y0 * y0 + y1 * y1;
            int   c = (y0 != 0.f) + (y1 != 0.f);
            for (int o = 32; o; o >>= 1) {
                p += __shfl_xor(p, o, 64);
                c += __shfl_xor(c, o, 64);
            }
            if (lane == 0) { wred[wid] = p; wredi[wid] = c; }   // wid 12..14
            cand[i >> 6][i & 63] = 0xFFFFFFFFu;
        } else {                          // wave 15: small inits
            const int j = i - 192;        // 0..63
            if (j < 3) s_cc[j] = 0;
            else if (j < 11) cnt8[j - 3] = 0;
            else if (j < 15) loss4[j - 11] = 0.f;
        }
        for (int h = i; h < 4096; h += 256) hist2[h] = 0u;
    }
    __syncthreads();

    // ---- phase 3: sim finalize (threads 0-191): combine partials, sliding
    //      norms from xpad boundary terms, argmax w/ carried norm ----
    if (tid < 192) {
        const float qn = sqrtf(wred[12] + wred[13] + wred[14]);
        const int b = tid * 5;
        float d0 = spart[b]     + spart[b + 960]     + spart[b + 1920]     + spart[b + 2880];
        float d1 = spart[b + 1] + spart[b + 961]     + spart[b + 1921]     + spart[b + 2881];
        float d2 = spart[b + 2] + spart[b + 962]     + spart[b + 1922]     + spart[b + 2882];
        float d3 = spart[b + 3] + spart[b + 963]     + spart[b + 1923]     + spart[b + 2883];
        float n0 = spart[b + 4] + spart[b + 964]     + spart[b + 1924]     + spart[b + 2884];
        const float x0 = xpad[4 * tid],       x1 = xpad[4 * tid + 1], x2 = xpad[4 * tid + 2];
        const float e0 = xpad[4 * tid + 384], e1 = xpad[4 * tid + 385], e2 = xpad[4 * tid + 386];
        const float n1 = n0 - x0 * x0 + e0 * e0;
        const float n2 = n1 - x1 * x1 + e1 * e1;
        const float n3 = n2 - x2 * x2 + e2 * e2;
        const int s0 = 4 * tid;
        float sim0 = d0 / (qn * sqrtf(n0) + EPSF);
        float sim1 = d1 / (qn * sqrtf(n1) + EPSF);
        float sim2 = d2 / (qn * sqrtf(n2) + EPSF);
        float sim3 = d3 / (qn * sqrtf(n3) + EPSF);
        float bv = sim0; int bs = s0; float bn = n0;
        if (s0 + 1 < NS && sim1 > bv) { bv = sim1; bs = s0 + 1; bn = n1; }
        if (s0 + 2 < NS && sim2 > bv) { bv = sim2; bs = s0 + 2; bn = n2; }
        if (s0 + 3 < NS && sim3 > bv) { bv = sim3; bs = s0 + 3; bn = n3; }
        for (int o = 32; o; o >>= 1) {
            float v2 = __shfl_xor(bv, o, 64);
            int   i2 = __shfl_xor(bs, o, 64);
            float nn2 = __shfl_xor(bn, o, 64);
            if (v2 > bv || (v2 == bv && i2 < bs)) { bv = v2; bs = i2; bn = nn2; }
        }
        if (lane == 0) { wred[wid] = bv; wredi[wid] = bs; wredn[wid] = bn; }
        if (tid == 0) s_sc[0] = qn;
    }
    if (tid == 960) ycnt[row] = wredi[12] + wredi[13] + wredi[14];
    __syncthreads();

    // ---- phase 4: combine the 3 sim waves ----
    if (tid == 0) {
        float v = wred[0]; int b = wredi[0]; float nn = wredn[0];
        for (int w = 1; w < 3; ++w)
            if (wred[w] > v || (wred[w] == v && wredi[w] < b)) {
                v = wred[w]; b = wredi[w]; nn = wredn[w];
            }
        s_theta = b;
        s_sc[1] = sqrtf(nn) * s_sc[0] + EPSF;   // dn
    }
    __syncthreads();
    const int theta = s_theta;
    const float dn = s_sc[1];

    // ---- phase 5: softmax denom (no max-pass; |z| <= 0.1 by Cauchy-Schwarz) ----
    if (tid < DD) {
        float xo = xpad[theta + tid];
        float ez = expf((xo * yr[tid] / dn) / TEMPER_F);
        float p = ez;
        for (int o = 32; o; o >>= 1) p += __shfl_xor(p, o, 64);
        if (lane == 0) wred[wid] = p;            // wid 0..5
    }
    __syncthreads();

    // ---- phase 6: xep direct (deterministic expf recompute; bit-identical) ----
    if (tid < 192) {
        const float S = wred[0] + wred[1] + wred[2] + wred[3] + wred[4] + wred[5];
        const int off = theta - (DD - 1);
        const int sj = 2 * tid - off;
        float a0 = 0.f, a1 = 0.f;
        if (sj >= 0 && sj < DD) {
            float xo = xpad[theta + sj];
            a0 = xo * (expf((xo * yr[sj] / dn) / TEMPER_F) / S);
        }
        if (sj + 1 >= 0 && sj + 1 < DD) {
            float xo = xpad[theta + sj + 1];
            a1 = xo * (expf((xo * yr[sj + 1] / dn) / TEMPER_F) / S);
        }
        xep[tid] = packh2(a0, a1);
    }
    __syncthreads();

    // ---- encoder: K-split 4x, f16 pairs, fdot2 ----
    {
        const int ks = tid >> 8;              // 0..3 (wave-uniform)
        const int c4 = tid & 255;
        const uint4* wq = (const uint4*)wencp + (size_t)(ks * 48) * 256 + c4;
        const u32* xb = xep + ks * 48;
        float4 acc = make_float4(0.f, 0.f, 0.f, 0.f);
#pragma unroll 8
        for (int j2 = 0; j2 < 48; ++j2) {
            u32 xv = xb[j2];                  // broadcast
            uint4 w = wq[(size_t)j2 * 256];
            acc.x = dot2(xv, w.x, acc.x);
            acc.y = dot2(xv, w.y, acc.y);
            acc.z = dot2(xv, w.z, acc.z);
            acc.w = dot2(xv, w.w, acc.w);
        }
        *(float4*)&part[ks][4 * c4] = acc;
    }
    __syncthreads();

    const float oh = part[0][tid] + part[1][tid] + part[2][tid] + part[3][tid]
                   + benc[tid];
    const u32 okey = ~flipf(oh);              // ascending key == descending h
    atomicAdd(&hist2[okey >> 20], 1u);        // hist2 pre-zeroed in phase 2
    __syncthreads();

    // ---- histogram select: exact boundary keys at ranks 255/511/767 ----
    {
        // hierarchical exclusive scan: 4 bins/thread
        const int t4 = tid << 2;
        const u32 l0 = hist2[t4], l1 = hist2[t4 + 1], l2 = hist2[t4 + 2], l3 = hist2[t4 + 3];
        const int s = (int)(l0 + l1 + l2 + l3);
        int inc = s;
        for (int o = 1; o < 64; o <<= 1) {
            int u = __shfl_up(inc, o, 64);
            if (lane >= o) inc += u;
        }
        if (lane == 63) wredi[wid] = inc;
        __syncthreads();
        if (tid == 0) {
            int acc = 0;
            for (int w = 0; w < 16; ++w) { wbase16[w] = acc; acc += wredi[w]; }
        }
        __syncthreads();
        const int c0 = wbase16[wid] + inc - s;            // cum before bin t4
        const int c1 = c0 + (int)l0, c2 = c1 + (int)l1, c3 = c2 + (int)l2;
        const int c4e = c3 + (int)l3;
#pragma unroll
        for (int i = 0; i < 3; ++i) {
            const int R = 255 + (i << 8);
            if (R >= c0 && R < c1)      { sbinB[i] = t4;     srankB[i] = R - c0; }
            else if (R >= c1 && R < c2) { sbinB[i] = t4 + 1; srankB[i] = R - c1; }
            else if (R >= c2 && R < c3) { sbinB[i] = t4 + 2; srankB[i] = R - c2; }
            else if (R >= c3 && R < c4e){ sbinB[i] = t4 + 3; srankB[i] = R - c3; }
        }
        __syncthreads();
        // extract candidates of the 3 boundary bins
        const int myb = (int)(okey >> 20);
#pragma unroll
        for (int i = 0; i < 3; ++i) {
            if (myb == sbinB[i]) {
                int slot = atomicAdd(&s_cc[i], 1);
                if (slot < 64) cand[i][slot] = okey;
            }
        }
        __syncthreads();
        // 3 waves each sort 64 candidates in-register; pick intra-bin rank
        if (wid < 3) {
            u32 v = cand[wid][lane];
            for (int k2 = 2; k2 <= 64; k2 <<= 1) {
                for (int j = k2 >> 1; j > 0; j >>= 1) {
                    u32 p = __shfl_xor(v, j, 64);
                    const bool takeMin = ((lane & j) == 0) == ((lane & k2) == 0);
                    v = takeMin ? (v < p ? v : p) : (v > p ? v : p);
                }
            }
            if (lane == srankB[wid]) s_b[wid] = v;
        }
        __syncthreads();
    }
    const u32 b1 = s_b[0], b2 = s_b[1], b3 = s_b[2];

    // ---- partition: class = 2*quartile + (below-cutoff); ballot compaction ----
    {
        const int myk = (okey <= b1) ? 0 : (okey <= b2) ? 1 : (okey <= b3) ? 2 : 3;
        const int cls = 2 * myk + ((oh > CUTF) ? 0 : 1);
        int myprefix = 0;
        const u64 ltmask = (1ull << lane) - 1;
#pragma unroll
        for (int c = 0; c < 8; ++c) {
            u64 m = __ballot(cls == c);
            if (cls == c) myprefix = __popcll(m & ltmask);
            if (lane == 0) {
                wcls[c * 16 + wid] = (int)__popcll(m);
                atomicAdd(&cnt8[c], (int)__popcll(m));
            }
        }
        __syncthreads();
        if (tid < 128) {
            int v = wcls[tid];
            int inc = v;
            for (int o = 1; o < 64; o <<= 1) {
                int t2 = __shfl_up(inc, o, 64);
                if (lane >= o) inc += t2;
            }
            sbase[tid] = inc - v;             // wave-local exclusive
        }
        __syncthreads();
        if (tid >= 64 && tid < 128) sbase[tid] += sbase[63] + wcls[63];
        __syncthreads();
        const int slot = sbase[cls * 16 + wid] + myprefix;
        dec2[slot] = make_uint2(__float_as_uint(oh), (u32)tid * 192u);
    }
    __syncthreads();

    // ---- decode pass 1: 8 groups of 128 thr = (k, rank-half); 4 cols/thread ----
    // f16 weights, entries consumed in PAIRS via v_dot2_f32_f16.
    {
        const int g8 = tid >> 7;              // 0..7
        const int k  = g8 >> 1;               // wave-uniform
        const int hf = g8 & 1;
        const int gg = tid & 127;
        const bool active = (gg < 96);        // 96 col-quads = 384 cols
        int n = 0;
        if (active) n = (k == 0) ? CD : cnt8[2 * k];
        int r  = hf * 128;
        int r1 = n < r + 128 ? n : r + 128;
        if (r1 < r) r1 = r;
        float4 acc = make_float4(0.f, 0.f, 0.f, 0.f);
        const u32* wd = wdec16 + 2 * gg;      // col-pairs 2gg, 2gg+1
        const int base = k * CD;
        for (; r + 8 <= r1; r += 8) {
#pragma unroll
            for (int q = 0; q < 8; q += 2) {
                uint4 dv = *(const uint4*)&dec2[base + r + q];
                u32 vp = packh2(__uint_as_float(dv.x), __uint_as_float(dv.z));
                uint2 w0 = *(const uint2*)(wd + dv.y);
                uint2 w1 = *(const uint2*)(wd + dv.w);
                u32 p0 = (w0.x & 0xffffu) | (w1.x << 16);      // col 4gg
                u32 p1 = (w0.x >> 16) | (w1.x & 0xffff0000u);  // col 4gg+1
                u32 p2 = (w0.y & 0xffffu) | (w1.y << 16);      // col 4gg+2
                u32 p3 = (w0.y >> 16) | (w1.y & 0xffff0000u);  // col 4gg+3
                acc.x = dot2(vp, p0, acc.x);
                acc.y = dot2(vp, p1, acc.y);
                acc.z = dot2(vp, p2, acc.z);
                acc.w = dot2(vp, p3, acc.w);
            }
        }
        for (; r + 2 <= r1; r += 2) {
            uint4 dv = *(const uint4*)&dec2[base + r];
            u32 vp = packh2(__uint_as_float(dv.x), __uint_as_float(dv.z));
            uint2 w0 = *(const uint2*)(wd + dv.y);
            uint2 w1 = *(const uint2*)(wd + dv.w);
            u32 p0 = (w0.x & 0xffffu) | (w1.x << 16);
            u32 p1 = (w0.x >> 16) | (w1.x & 0xffff0000u);
            u32 p2 = (w0.y & 0xffffu) | (w1.y << 16);
            u32 p3 = (w0.y >> 16) | (w1.y & 0xffff0000u);
            acc.x = dot2(vp, p0, acc.x);
            acc.y = dot2(vp, p1, acc.y);
            acc.z = dot2(vp, p2, acc.z);
            acc.w = dot2(vp, p3, acc.w);
        }
        if (r < r1) {                          // odd single entry
            uint2 dv = dec2[base + r];
            float v0 = __uint_as_float(dv.x);
            uint2 w0 = *(const uint2*)(wd + dv.y);
            u32 vlo = packh2(v0, 0.f), vhi = packh2(0.f, v0);
            acc.x = dot2(vlo, w0.x, acc.x);
            acc.y = dot2(vhi, w0.x, acc.y);
            acc.z = dot2(vlo, w0.y, acc.z);
            acc.w = dot2(vhi, w0.y, acc.w);
        }
        if (active) dpart[g8][gg] = acc;
    }
    __syncthreads();

    // ---- decode pass 2: combine halves, store, loss ----
    {
        float l = 0.f;
        if (tid < 512) {
            const int k2 = tid >> 7;          // wave-uniform
            const int q  = tid & 127;
            if (q < 96) {
                float4 a = dpart[2 * k2][q];
                float4 b = dpart[2 * k2 + 1][q];
                float4 bb = *(const float4*)&bdec[4 * q];
                float4 o4;
                o4.x = a.x + b.x + bb.x;
                o4.y = a.y + b.y + bb.y;
                o4.z = a.z + b.z + bb.z;
                o4.w = a.w + b.w + bb.w;
                *(float4*)&out_xdis[((size_t)k2 * NROWS + row) * DD + 4 * q] = o4;
                float4 xv = *(const float4*)&xrow[4 * q];
                float4 yv = *(const float4*)&yr[4 * q];
                float ee;
                ee = o4.x - xv.x; if (yv.x != 0.f) l += ee * ee;
                ee = o4.y - xv.y; if (yv.y != 0.f) l += ee * ee;
                ee = o4.z - xv.z; if (yv.z != 0.f) l += ee * ee;
                ee = o4.w - xv.w; if (yv.w != 0.f) l += ee * ee;
            }
        }
        for (int o = 32; o; o >>= 1) l += __shfl_xor(l, o, 64);
        if (tid < 512 && lane == 0) atomicAdd(&loss4[tid >> 7], l);
    }
    __syncthreads();
    if (tid < NITER) lossp[row * NITER + tid] = loss4[tid];
}

// ---- finalize: losses[k] = sum_rows lossp / sum_rows ycnt ----
__global__ __launch_bounds__(256) void finalize2(
    const float* __restrict__ lossp, const int* __restrict__ ycnt,
    float* __restrict__ losses)
{
    const int tid = threadIdx.x, lane = tid & 63, w = tid >> 6;
    __shared__ int ctot[4];
    int c = ycnt[tid];
    for (int o = 32; o; o >>= 1) c += __shfl_xor(c, o, 64);
    if (lane == 0) ctot[w] = c;
    __syncthreads();
    const int total = ctot[0] + ctot[1] + ctot[2] + ctot[3];
    float s = lossp[lane * NITER + w] + lossp[(lane + 64) * NITER + w]
            + lossp[(lane + 128) * NITER + w] + lossp[(lane + 192) * NITER + w];
    for (int o = 32; o; o >>= 1) s += __shfl_xor(s, o, 64);
    if (lane == 0) losses[w] = s / (float)total;
}

extern "C" void kernel_launch(void* const* d_in, const int* in_sizes, int n_in,
                              void* d_out, int out_size, void* d_ws, size_t ws_size,
                              hipStream_t stream) {
    const float* x    = (const float*)d_in[0];
    const float* y    = (const float*)d_in[1];
    const float* Wenc = (const float*)d_in[2];
    const float* benc = (const float*)d_in[3];
    const float* Wdec = (const float*)d_in[4];
    const float* bdec = (const float*)d_in[5];

    float* out  = (float*)d_out;
    float* loss = out + (out_size - NITER);

    // workspace (all regions fully written before read each launch; 16B-aligned)
    float* lossp  = (float*)d_ws;                          // 1024 floats
    int*   ycnt   = (int*)(lossp + NROWS * NITER);         // 256 ints
    u32*   wencp  = (u32*)(ycnt + NROWS);                  // 196608 u32 (f16 K-pairs)
    u32*   wdec16 = wencp + 192 * HD;                      // 196608 u32 (f16 col-pairs)

    convert_kernel<<<256, 256, 0, stream>>>(Wenc, Wdec, (uint4*)wencp,
                                            (uint2*)wdec16);
    fused_kernel<<<NROWS, 1024, 0, stream>>>(x, y, wencp, benc, wdec16, bdec,
                                             out, lossp, ycnt);
    finalize2<<<1, 256, 0, stream>>>(lossp, ycnt, loss);
}

// Round 3
// 99.126 us; speedup vs baseline: 1.0166x; 1.0011x over previous
//
#include <hip/hip_runtime.h>
#include <hip/hip_fp16.h>
#include <math.h>

#define DD 384
#define HD 1024
#define CD 256
#define NS 765        // 2*DD-1 shifts
#define NITER 4
#define NROWS 256     // B*T
#define TEMPER_F 10.0f
#define EPSF 1e-6f
#define CUTF 1e-10f
#define NPRE 12       // encoder weight prefetch depth (uint4 per thread)

typedef unsigned long long u64;
typedef unsigned int u32;
typedef _Float16 hh2 __attribute__((ext_vector_type(2)));

// monotone float->uint (ascending)
__device__ __forceinline__ u32 flipf(float f) {
    u32 u = __float_as_uint(f);
    return u ^ ((u32)((int)u >> 31) | 0x80000000u);
}
// fp32 pair -> packed f16
__device__ __forceinline__ u32 packh2(float a, float b) {
    __half2 p = __floats2half2_rn(a, b);
    return __builtin_bit_cast(u32, p);
}
// fp32 += dot2(f16x2, f16x2)
__device__ __forceinline__ float dot2(u32 a, u32 b, float c) {
#if __has_builtin(__builtin_amdgcn_fdot2)
    return __builtin_amdgcn_fdot2(__builtin_bit_cast(hh2, a),
                                  __builtin_bit_cast(hh2, b), c, false);
#else
    __half2 ah = __builtin_bit_cast(__half2, a);
    __half2 bh = __builtin_bit_cast(__half2, b);
    return fmaf(__half2float(ah.y), __half2float(bh.y),
           fmaf(__half2float(ah.x), __half2float(bh.x), c));
#endif
}

// ---- 0) convert weights: Wenc -> f16 K-paired [192][1024] u32 (as uint4 quads);
//         Wdec -> f16 col-paired [1024][192] u32 ----
__global__ __launch_bounds__(256) void convert_kernel(
    const float* __restrict__ We, const float* __restrict__ Wd,
    uint4* __restrict__ wencp4, uint2* __restrict__ wd16)
{
    const int t = blockIdx.x * 256 + threadIdx.x;      // 65536 threads
    if (t < 192 * 256) {                               // row-pair j2, col-quad c4
        const int j2 = t >> 8, c4 = t & 255;
        float4 a = *(const float4*)&We[(2 * j2)     * HD + 4 * c4];
        float4 b = *(const float4*)&We[(2 * j2 + 1) * HD + 4 * c4];
        wencp4[j2 * 256 + c4] = make_uint4(packh2(a.x, b.x), packh2(a.y, b.y),
                                           packh2(a.z, b.z), packh2(a.w, b.w));
    }
    for (int i = t; i < (HD * DD) / 4; i += 65536) {
        float4 v = ((const float4*)Wd)[i];
        wd16[i] = make_uint2(packh2(v.x, v.y), packh2(v.z, v.w));
    }
}

// One 1024-thread block per row. Latency-bound kernel (HBM 2%, VALU 22%):
// this revision targets serialization — encoder weight PREFETCH (12 uint4/thread
// issued at kernel top, stream overlaps front phases), uint4 histogram-scan read
// (was 8-way bank conflict), 16-lane parallel wbase16 scan (was serial tid==0
// LDS-latency chain), phase-4 barrier removed (theta/dn recomputed per-thread,
// deterministic), decode pass-2 bias/x prefetch. All arithmetic bit-identical.
// NOTE: loss/ycnt leave the kernel as plain per-row stores; finalize is a
// separate dispatch. Agent-scope fences/atomics in-kernel regressed 3x (R6,R15).
__global__ __launch_bounds__(1024) void fused_kernel(
    const float* __restrict__ x, const float* __restrict__ y,
    const u32* __restrict__ wencp, const float* __restrict__ benc,
    const u32* __restrict__ wdec16, const float* __restrict__ bdec,
    float* __restrict__ out_xdis, float* __restrict__ lossp,
    int* __restrict__ ycnt)
{
    const int row  = blockIdx.x;
    const int tid  = threadIdx.x;
    const int lane = tid & 63;
    const int wid  = tid >> 6;       // 0..15

    __shared__ __align__(16) float xpad[1152];
    __shared__ __align__(16) float yr[DD];
    __shared__ u32   xep[192];                    // xe packed f16 pairs
    __shared__ __align__(16) float part[4][HD];   // enc partials
    __shared__ __align__(16) u32   hist2[4096];   // dedicated histogram
    __shared__ float spart[4 * 192 * 5];          // sim partials {d0..d3,n}
    __shared__ __align__(16) uint2 dec2[HD];      // {bits(v), idx*192}
    __shared__ __align__(16) float4 dpart[8][96]; // decode half-partials
    __shared__ float wred[16];
    __shared__ int   wredi[16];
    __shared__ int   wbase16[16];
    __shared__ float s_bv[3];                     // sim wave bests (value)
    __shared__ int   s_bi[3];                     // sim wave bests (shift)
    __shared__ float s_bn[3];                     // sim wave bests (norm)
    __shared__ float s_sc[4];
    __shared__ int   s_theta;
    __shared__ u32   s_b[3];
    __shared__ int   sbinB[3], srankB[3], s_cc[3];
    __shared__ u32   cand[3][64];
    __shared__ int   wcls[128];                   // per (class, wave) counts
    __shared__ int   sbase[128];                  // exclusive scan
    __shared__ int   cnt8[8];
    __shared__ float loss4[NITER];

    const float* xrow = x + row * DD;
    const float* yrow = y + row * DD;

    // ---- encoder weight prefetch: independent of every front phase; plain
    //      register loads are NOT drained at barriers, so the 192KB/block
    //      stream overlaps prep/sim and shrinks the encoder phase ----
    const int eks = tid >> 8;             // 0..3 (wave-uniform)
    const int ec4 = tid & 255;
    const uint4* wq = (const uint4*)wencp + (size_t)(eks * 48) * 256 + ec4;
    uint4 wpre[NPRE];
#pragma unroll
    for (int p = 0; p < NPRE; ++p) wpre[p] = wq[(size_t)p * 256];
    const float bpre = benc[tid];

    // ---- phase 1: prep ----
    for (int i = tid; i < 1152; i += 1024)
        xpad[i] = (i >= DD - 1 && i < 2 * DD - 1) ? xrow[i - (DD - 1)] : 0.f;
    if (tid < DD) yr[tid] = yrow[tid];
    __syncthreads();

    // ---- phase 2: sim partials (waves 0-11) || y-norm + zero/init (12-15) ----
    if (tid < 768) {
        const int qid = tid / 192, t = tid - qid * 192;  // qid wave-uniform
        const int jb = 24 * qid;
        const float4* xp4 = (const float4*)xpad;
        const float4* yp4 = (const float4*)yr;
        float4 A = xp4[t + jb];
        float d0 = 0.f, d1 = 0.f, d2 = 0.f, d3 = 0.f, n0 = 0.f;
#pragma unroll 8
        for (int jc = 0; jc < 24; ++jc) {
            float4 B = xp4[t + jb + jc + 1];
            float4 Y = yp4[jb + jc];
            d0 += A.x * Y.x; d0 += A.y * Y.y; d0 += A.z * Y.z; d0 += A.w * Y.w;
            d1 += A.y * Y.x; d1 += A.z * Y.y; d1 += A.w * Y.z; d1 += B.x * Y.w;
            d2 += A.z * Y.x; d2 += A.w * Y.y; d2 += B.x * Y.z; d2 += B.y * Y.w;
            d3 += A.w * Y.x; d3 += B.x * Y.y; d3 += B.y * Y.z; d3 += B.z * Y.w;
            n0 += A.x * A.x; n0 += A.y * A.y; n0 += A.z * A.z; n0 += A.w * A.w;
            A = B;
        }
        float* sp = &spart[(qid * 192 + t) * 5];
        sp[0] = d0; sp[1] = d1; sp[2] = d2; sp[3] = d3; sp[4] = n0;
    } else {
        const int i = tid - 768;          // 0..255 (waves 12-15)
        if (i < 192) {                    // waves 12-14: y^2 + count
            float y0 = yr[2 * i], y1 = yr[2 * i + 1];
            float p = y0 * y0 + y1 * y1;
            int   c = (y0 != 0.f) + (y1 != 0.f);
            for (int o = 32; o; o >>= 1) {
                p += __shfl_xor(p, o, 64);
                c += __shfl_xor(c, o, 64);
            }
            if (lane == 0) { wred[wid] = p; wredi[wid] = c; }   // wid 12..14
            cand[i >> 6][i & 63] = 0xFFFFFFFFu;
        } else {                          // wave 15: small inits
            const int j = i - 192;        // 0..63
            if (j < 3) s_cc[j] = 0;
            else if (j < 11) cnt8[j - 3] = 0;
            else if (j < 15) loss4[j - 11] = 0.f;
        }
        for (int h = i; h < 4096; h += 256) hist2[h] = 0u;
    }
    __syncthreads();

    // ---- phase 3: sim finalize (threads 0-191): combine partials, sliding
    //      norms from xpad boundary terms, argmax w/ carried norm ----
    if (tid < 192) {
        const float qn = sqrtf(wred[12] + wred[13] + wred[14]);
        const int b = tid * 5;
        float d0 = spart[b]     + spart[b + 960] + spart[b + 1920] + spart[b + 2880];
        float d1 = spart[b + 1] + spart[b + 961] + spart[b + 1921] + spart[b + 2881];
        float d2 = spart[b + 2] + spart[b + 962] + spart[b + 1922] + spart[b + 2882];
        float d3 = spart[b + 3] + spart[b + 963] + spart[b + 1923] + spart[b + 2883];
        float n0 = spart[b + 4] + spart[b + 964] + spart[b + 1924] + spart[b + 2884];
        const float x0 = xpad[4 * tid],       x1 = xpad[4 * tid + 1], x2 = xpad[4 * tid + 2];
        const float e0 = xpad[4 * tid + 384], e1 = xpad[4 * tid + 385], e2 = xpad[4 * tid + 386];
        const float n1 = n0 - x0 * x0 + e0 * e0;
        const float n2 = n1 - x1 * x1 + e1 * e1;
        const float n3 = n2 - x2 * x2 + e2 * e2;
        const int s0 = 4 * tid;
        float sim0 = d0 / (qn * sqrtf(n0) + EPSF);
        float sim1 = d1 / (qn * sqrtf(n1) + EPSF);
        float sim2 = d2 / (qn * sqrtf(n2) + EPSF);
        float sim3 = d3 / (qn * sqrtf(n3) + EPSF);
        float bv = sim0; int bs = s0; float bn = n0;
        if (s0 + 1 < NS && sim1 > bv) { bv = sim1; bs = s0 + 1; bn = n1; }
        if (s0 + 2 < NS && sim2 > bv) { bv = sim2; bs = s0 + 2; bn = n2; }
        if (s0 + 3 < NS && sim3 > bv) { bv = sim3; bs = s0 + 3; bn = n3; }
        for (int o = 32; o; o >>= 1) {
            float v2 = __shfl_xor(bv, o, 64);
            int   i2 = __shfl_xor(bs, o, 64);
            float nn2 = __shfl_xor(bn, o, 64);
            if (v2 > bv || (v2 == bv && i2 < bs)) { bv = v2; bs = i2; bn = nn2; }
        }
        if (lane == 0) { s_bv[wid] = bv; s_bi[wid] = bs; s_bn[wid] = bn; }
    }
    if (tid == 960) ycnt[row] = wredi[12] + wredi[13] + wredi[14];
    __syncthreads();

    // ---- phase 5: theta/dn per-thread (deterministic 3-way combine; no extra
    //      barrier) + softmax denom (no max-pass; |z| <= 0.1 Cauchy-Schwarz) ----
    if (tid < DD) {
        const float qn2 = sqrtf(wred[12] + wred[13] + wred[14]);
        float v = s_bv[0]; int b = s_bi[0]; float nn = s_bn[0];
        if (s_bv[1] > v || (s_bv[1] == v && s_bi[1] < b)) { v = s_bv[1]; b = s_bi[1]; nn = s_bn[1]; }
        if (s_bv[2] > v || (s_bv[2] == v && s_bi[2] < b)) { v = s_bv[2]; b = s_bi[2]; nn = s_bn[2]; }
        const int th = b;
        const float dnl = sqrtf(nn) * qn2 + EPSF;
        float xo = xpad[th + tid];
        float ez = expf((xo * yr[tid] / dnl) / TEMPER_F);
        float p = ez;
        for (int o = 32; o; o >>= 1) p += __shfl_xor(p, o, 64);
        if (lane == 0) wred[wid] = p;            // wid 0..5 (sim slots now dead)
        if (tid == 0) { s_theta = th; s_sc[1] = dnl; }
    }
    __syncthreads();

    // ---- phase 6: xep direct (deterministic expf recompute; bit-identical) ----
    if (tid < 192) {
        const int theta = s_theta;
        const float dn = s_sc[1];
        const float S = wred[0] + wred[1] + wred[2] + wred[3] + wred[4] + wred[5];
        const int off = theta - (DD - 1);
        const int sj = 2 * tid - off;
        float a0 = 0.f, a1 = 0.f;
        if (sj >= 0 && sj < DD) {
            float xo = xpad[theta + sj];
            a0 = xo * (expf((xo * yr[sj] / dn) / TEMPER_F) / S);
        }
        if (sj + 1 >= 0 && sj + 1 < DD) {
            float xo = xpad[theta + sj + 1];
            a1 = xo * (expf((xo * yr[sj + 1] / dn) / TEMPER_F) / S);
        }
        xep[tid] = packh2(a0, a1);
    }
    __syncthreads();

    // ---- encoder: K-split 4x, f16 pairs, fdot2; first NPRE from prefetch ----
    {
        const u32* xb = xep + eks * 48;
        float4 acc = make_float4(0.f, 0.f, 0.f, 0.f);
#pragma unroll
        for (int p = 0; p < NPRE; ++p) {
            u32 xv = xb[p];                   // broadcast
            acc.x = dot2(xv, wpre[p].x, acc.x);
            acc.y = dot2(xv, wpre[p].y, acc.y);
            acc.z = dot2(xv, wpre[p].z, acc.z);
            acc.w = dot2(xv, wpre[p].w, acc.w);
        }
#pragma unroll 6
        for (int j2 = NPRE; j2 < 48; ++j2) {
            u32 xv = xb[j2];                  // broadcast
            uint4 w = wq[(size_t)j2 * 256];
            acc.x = dot2(xv, w.x, acc.x);
            acc.y = dot2(xv, w.y, acc.y);
            acc.z = dot2(xv, w.z, acc.z);
            acc.w = dot2(xv, w.w, acc.w);
        }
        *(float4*)&part[eks][4 * ec4] = acc;
    }
    __syncthreads();

    const float oh = part[0][tid] + part[1][tid] + part[2][tid] + part[3][tid]
                   + bpre;
    const u32 okey = ~flipf(oh);              // ascending key == descending h
    atomicAdd(&hist2[okey >> 20], 1u);        // hist2 pre-zeroed in phase 2
    __syncthreads();

    // ---- histogram select: exact boundary keys at ranks 255/511/767 ----
    {
        // hierarchical exclusive scan: 4 bins/thread (uint4: conflict-free)
        const int t4 = tid << 2;
        const uint4 h4 = *(const uint4*)&hist2[t4];
        const u32 l0 = h4.x, l1 = h4.y, l2 = h4.z, l3 = h4.w;
        const int s = (int)(l0 + l1 + l2 + l3);
        int inc = s;
        for (int o = 1; o < 64; o <<= 1) {
            int u = __shfl_up(inc, o, 64);
            if (lane >= o) inc += u;
        }
        if (lane == 63) wredi[wid] = inc;
        __syncthreads();
        if (tid < 64) {                       // 16-lane parallel scan (wave 0)
            int vv = (lane < 16) ? wredi[lane] : 0;
            int pr = vv;
            for (int o = 1; o < 16; o <<= 1) {
                int u2 = __shfl_up(pr, o, 64);
                if (lane >= o) pr += u2;
            }
            if (lane < 16) wbase16[lane] = pr - vv;
        }
        __syncthreads();
        const int c0 = wbase16[wid] + inc - s;            // cum before bin t4
        const int c1 = c0 + (int)l0, c2 = c1 + (int)l1, c3 = c2 + (int)l2;
        const int c4e = c3 + (int)l3;
#pragma unroll
        for (int i = 0; i < 3; ++i) {
            const int R = 255 + (i << 8);
            if (R >= c0 && R < c1)      { sbinB[i] = t4;     srankB[i] = R - c0; }
            else if (R >= c1 && R < c2) { sbinB[i] = t4 + 1; srankB[i] = R - c1; }
            else if (R >= c2 && R < c3) { sbinB[i] = t4 + 2; srankB[i] = R - c2; }
            else if (R >= c3 && R < c4e){ sbinB[i] = t4 + 3; srankB[i] = R - c3; }
        }
        __syncthreads();
        // extract candidates of the 3 boundary bins
        const int myb = (int)(okey >> 20);
#pragma unroll
        for (int i = 0; i < 3; ++i) {
            if (myb == sbinB[i]) {
                int slot = atomicAdd(&s_cc[i], 1);
                if (slot < 64) cand[i][slot] = okey;
            }
        }
        __syncthreads();
        // 3 waves each sort 64 candidates in-register; pick intra-bin rank
        if (wid < 3) {
            u32 v = cand[wid][lane];
            for (int k2 = 2; k2 <= 64; k2 <<= 1) {
                for (int j = k2 >> 1; j > 0; j >>= 1) {
                    u32 p = __shfl_xor(v, j, 64);
                    const bool takeMin = ((lane & j) == 0) == ((lane & k2) == 0);
                    v = takeMin ? (v < p ? v : p) : (v > p ? v : p);
                }
            }
            if (lane == srankB[wid]) s_b[wid] = v;
        }
        __syncthreads();
    }
    const u32 b1 = s_b[0], b2 = s_b[1], b3 = s_b[2];

    // ---- partition: class = 2*quartile + (below-cutoff); ballot compaction ----
    {
        const int myk = (okey <= b1) ? 0 : (okey <= b2) ? 1 : (okey <= b3) ? 2 : 3;
        const int cls = 2 * myk + ((oh > CUTF) ? 0 : 1);
        int myprefix = 0;
        const u64 ltmask = (1ull << lane) - 1;
#pragma unroll
        for (int c = 0; c < 8; ++c) {
            u64 m = __ballot(cls == c);
            if (cls == c) myprefix = __popcll(m & ltmask);
            if (lane == 0) {
                wcls[c * 16 + wid] = (int)__popcll(m);
                atomicAdd(&cnt8[c], (int)__popcll(m));
            }
        }
        __syncthreads();
        if (tid < 128) {
            int v = wcls[tid];
            int inc = v;
            for (int o = 1; o < 64; o <<= 1) {
                int t2 = __shfl_up(inc, o, 64);
                if (lane >= o) inc += t2;
            }
            sbase[tid] = inc - v;             // wave-local exclusive
        }
        __syncthreads();
        if (tid >= 64 && tid < 128) sbase[tid] += sbase[63] + wcls[63];
        __syncthreads();
        const int slot = sbase[cls * 16 + wid] + myprefix;
        dec2[slot] = make_uint2(__float_as_uint(oh), (u32)tid * 192u);
    }
    __syncthreads();

    // ---- decode pass 1: 8 groups of 128 thr = (k, rank-half); 4 cols/thread ----
    // f16 weights, entries consumed in PAIRS via v_dot2_f32_f16.
    // Pass-2 bias/x prefetched here so their latency hides under the loop.
    float4 bb_pre = make_float4(0.f, 0.f, 0.f, 0.f);
    float4 xv_pre = make_float4(0.f, 0.f, 0.f, 0.f);
    {
        const int qp = tid & 127;
        if (tid < 512 && qp < 96) {
            bb_pre = *(const float4*)&bdec[4 * qp];
            xv_pre = *(const float4*)&xrow[4 * qp];
        }
    }
    {
        const int g8 = tid >> 7;              // 0..7
        const int k  = g8 >> 1;               // wave-uniform
        const int hf = g8 & 1;
        const int gg = tid & 127;
        const bool active = (gg < 96);        // 96 col-quads = 384 cols
        int n = 0;
        if (active) n = (k == 0) ? CD : cnt8[2 * k];
        int r  = hf * 128;
        int r1 = n < r + 128 ? n : r + 128;
        if (r1 < r) r1 = r;
        float4 acc = make_float4(0.f, 0.f, 0.f, 0.f);
        const u32* wd = wdec16 + 2 * gg;      // col-pairs 2gg, 2gg+1
        const int base = k * CD;
        for (; r + 8 <= r1; r += 8) {
#pragma unroll
            for (int q = 0; q < 8; q += 2) {
                uint4 dv = *(const uint4*)&dec2[base + r + q];
                u32 vp = packh2(__uint_as_float(dv.x), __uint_as_float(dv.z));
                uint2 w0 = *(const uint2*)(wd + dv.y);
                uint2 w1 = *(const uint2*)(wd + dv.w);
                u32 p0 = (w0.x & 0xffffu) | (w1.x << 16);      // col 4gg
                u32 p1 = (w0.x >> 16) | (w1.x & 0xffff0000u);  // col 4gg+1
                u32 p2 = (w0.y & 0xffffu) | (w1.y << 16);      // col 4gg+2
                u32 p3 = (w0.y >> 16) | (w1.y & 0xffff0000u);  // col 4gg+3
                acc.x = dot2(vp, p0, acc.x);
                acc.y = dot2(vp, p1, acc.y);
                acc.z = dot2(vp, p2, acc.z);
                acc.w = dot2(vp, p3, acc.w);
            }
        }
        for (; r + 2 <= r1; r += 2) {
            uint4 dv = *(const uint4*)&dec2[base + r];
            u32 vp = packh2(__uint_as_float(dv.x), __uint_as_float(dv.z));
            uint2 w0 = *(const uint2*)(wd + dv.y);
            uint2 w1 = *(const uint2*)(wd + dv.w);
            u32 p0 = (w0.x & 0xffffu) | (w1.x << 16);
            u32 p1 = (w0.x >> 16) | (w1.x & 0xffff0000u);
            u32 p2 = (w0.y & 0xffffu) | (w1.y << 16);
            u32 p3 = (w0.y >> 16) | (w1.y & 0xffff0000u);
            acc.x = dot2(vp, p0, acc.x);
            acc.y = dot2(vp, p1, acc.y);
            acc.z = dot2(vp, p2, acc.z);
            acc.w = dot2(vp, p3, acc.w);
        }
        if (r < r1) {                          // odd single entry
            uint2 dv = dec2[base + r];
            float v0 = __uint_as_float(dv.x);
            uint2 w0 = *(const uint2*)(wd + dv.y);
            u32 vlo = packh2(v0, 0.f), vhi = packh2(0.f, v0);
            acc.x = dot2(vlo, w0.x, acc.x);
            acc.y = dot2(vhi, w0.x, acc.y);
            acc.z = dot2(vlo, w0.y, acc.z);
            acc.w = dot2(vhi, w0.y, acc.w);
        }
        if (active) dpart[g8][gg] = acc;
    }
    __syncthreads();

    // ---- decode pass 2: combine halves, store, loss ----
    {
        float l = 0.f;
        if (tid < 512) {
            const int k2 = tid >> 7;          // wave-uniform
            const int q  = tid & 127;
            if (q < 96) {
                float4 a = dpart[2 * k2][q];
                float4 b = dpart[2 * k2 + 1][q];
                float4 o4;
                o4.x = a.x + b.x + bb_pre.x;
                o4.y = a.y + b.y + bb_pre.y;
                o4.z = a.z + b.z + bb_pre.z;
                o4.w = a.w + b.w + bb_pre.w;
                *(float4*)&out_xdis[((size_t)k2 * NROWS + row) * DD + 4 * q] = o4;
                float4 yv = *(const float4*)&yr[4 * q];
                float ee;
                ee = o4.x - xv_pre.x; if (yv.x != 0.f) l += ee * ee;
                ee = o4.y - xv_pre.y; if (yv.y != 0.f) l += ee * ee;
                ee = o4.z - xv_pre.z; if (yv.z != 0.f) l += ee * ee;
                ee = o4.w - xv_pre.w; if (yv.w != 0.f) l += ee * ee;
            }
        }
        for (int o = 32; o; o >>= 1) l += __shfl_xor(l, o, 64);
        if (tid < 512 && lane == 0) atomicAdd(&loss4[tid >> 7], l);
    }
    __syncthreads();
    if (tid < NITER) lossp[row * NITER + tid] = loss4[tid];
}

// ---- finalize: losses[k] = sum_rows lossp / sum_rows ycnt ----
__global__ __launch_bounds__(256) void finalize2(
    const float* __restrict__ lossp, const int* __restrict__ ycnt,
    float* __restrict__ losses)
{
    const int tid = threadIdx.x, lane = tid & 63, w = tid >> 6;
    __shared__ int ctot[4];
    int c = ycnt[tid];
    for (int o = 32; o; o >>= 1) c += __shfl_xor(c, o, 64);
    if (lane == 0) ctot[w] = c;
    __syncthreads();
    const int total = ctot[0] + ctot[1] + ctot[2] + ctot[3];
    float s = lossp[lane * NITER + w] + lossp[(lane + 64) * NITER + w]
            + lossp[(lane + 128) * NITER + w] + lossp[(lane + 192) * NITER + w];
    for (int o = 32; o; o >>= 1) s += __shfl_xor(s, o, 64);
    if (lane == 0) losses[w] = s / (float)total;
}

extern "C" void kernel_launch(void* const* d_in, const int* in_sizes, int n_in,
                              void* d_out, int out_size, void* d_ws, size_t ws_size,
                              hipStream_t stream) {
    const float* x    = (const float*)d_in[0];
    const float* y    = (const float*)d_in[1];
    const float* Wenc = (const float*)d_in[2];
    const float* benc = (const float*)d_in[3];
    const float* Wdec = (const float*)d_in[4];
    const float* bdec = (const float*)d_in[5];

    float* out  = (float*)d_out;
    float* loss = out + (out_size - NITER);

    // workspace (all regions fully written before read each launch; 16B-aligned)
    float* lossp  = (float*)d_ws;                          // 1024 floats
    int*   ycnt   = (int*)(lossp + NROWS * NITER);         // 256 ints
    u32*   wencp  = (u32*)(ycnt + NROWS);                  // 196608 u32 (f16 K-pairs)
    u32*   wdec16 = wencp + 192 * HD;                      // 196608 u32 (f16 col-pairs)

    convert_kernel<<<256, 256, 0, stream>>>(Wenc, Wdec, (uint4*)wencp,
                                            (uint2*)wdec16);
    fused_kernel<<<NROWS, 1024, 0, stream>>>(x, y, wencp, benc, wdec16, bdec,
                                             out, lossp, ycnt);
    finalize2<<<1, 256, 0, stream>>>(lossp, ycnt, loss);
}